// Round 11
// baseline (60.161 us; speedup 1.0000x reference)
//
#include <hip/hip_runtime.h>

#define NP      8192
#define NCG     20
#define NC3     8000        // 20^3 unit cells over [0,20)^3
#define SCAP    4608        // compact occupied-pred capacity (~4096 expected)
#define NBLK    64          // blocks
#define ROWS_PB 128         // rows per block (512 threads, 4 lanes/row)
#define SEG_PB  256         // fixed entry segment per block (deterministic)
#define ECAP    (NBLK*SEG_PB)   // 16384
#define CAP     16          // per-row candidate cap (pos fits 4 bits)
#define INF_U   0xFFFFFFFFu

// ---- shared-memory overlay offsets (build phase) ----
#define OFF_SPRED   0           // 73728  float4[SCAP]
#define OFF_CC      73728       // 32000  int[NC3]
#define OFF_CSTART  105728      // 16002  u16[NC3+1]
#define OFF_SKEY    121736      // 16384  u64[ROWS_PB*CAP]
#define OFF_SCNT    138120      // 512    int[ROWS_PB]
#define OFF_SST     138632      // 512    int[ROWS_PB]
#define OFF_WT      139144      // 32     int[8]
#define OFF_WTOT    139176      // 8      int[2]
#define SMEM_BYTES  139200
// ---- overlay (matcher tail; build data dead) ----
#define OFF_E       0           // 32768  u16[ECAP]
#define OFF_O0S     32768       // 16384  u16[NP]
#define OFF_CN8     49152      // 8192   u8[NP]
#define OFF_HS      57344       // 32768  u32[NP]
#define OFF_REDF    90112       // 64     float[2][8]
#define OFF_REDI    90176       // 64     int[2][8]

// Single fused kernel: 64 blocks self-bin + build candidates (all-LDS, fixed
// deterministic segments); the LAST block (done counter) overlays an LDS
// chain-following Gale-Shapley matcher + reduction. Fixed point == the
// reference's serial greedy scan (validated absmax=0.0, rounds 1-10).
__global__ __launch_bounds__(512)
void spl_fused(const float4* __restrict__ pred,
               const float4* __restrict__ truec,
               unsigned short* __restrict__ o0g,   // row -> entry start | 0xFFFE occ-none | 0xFFFF unocc
               unsigned char* __restrict__ cng,    // row -> candidate count
               unsigned short* __restrict__ Eg,    // ECAP entry cols (sorted per row)
               int* __restrict__ done,
               float* __restrict__ out) {
    __shared__ __align__(16) unsigned char smem[SMEM_BYTES];
    __shared__ int amLast;
    float4* spredL            = (float4*)(smem + OFF_SPRED);
    int* cc                   = (int*)(smem + OFF_CC);
    unsigned short* cellstart = (unsigned short*)(smem + OFF_CSTART);
    unsigned long long* skey  = (unsigned long long*)(smem + OFF_SKEY); // [g*CAP+a]
    int* scnt                 = (int*)(smem + OFF_SCNT);
    int* sst                  = (int*)(smem + OFF_SST);
    int* wt                   = (int*)(smem + OFF_WT);
    int* wtot                 = (int*)(smem + OFF_WTOT);

    int tid = threadIdx.x;
    int lane = tid & 63, wave = tid >> 6;

    for (int c = tid; c < NC3; c += 512) cc[c] = 0;
    __syncthreads();

    // pass 1: count occupied pred per cell, remember (cell, rank)
    int cell[16], rk[16];
    #pragma unroll
    for (int k = 0; k < 16; ++k) {
        int i = k * 512 + tid;
        float4 p = pred[i];
        if (p.w >= 0.5f) {
            int cx = min((int)p.x, NCG - 1);
            int cy = min((int)p.y, NCG - 1);
            int cz = min((int)p.z, NCG - 1);
            cell[k] = (cz * NCG + cy) * NCG + cx;
            rk[k] = atomicAdd(&cc[cell[k]], 1);
        } else cell[k] = -1;
    }
    __syncthreads();

    // exclusive scan of 8000 cell counts (serial-16 + wave shfl + 8-wave combine)
    int base16 = tid * 16;
    int loc[16]; int s = 0;
    #pragma unroll
    for (int k = 0; k < 16; ++k) {
        int c = base16 + k;
        int v = (c < NC3) ? cc[c] : 0;
        loc[k] = s; s += v;
    }
    int inc = s;
    #pragma unroll
    for (int o = 1; o < 64; o <<= 1) {
        int t = __shfl_up(inc, o);
        if (lane >= o) inc += t;
    }
    if (lane == 63) wt[wave] = inc;
    __syncthreads();
    if (tid < 8) {
        int v = wt[tid]; int iv = v;
        #pragma unroll
        for (int o = 1; o < 8; o <<= 1) {
            int t = __shfl_up(iv, o);
            if (tid >= o) iv += t;
        }
        wt[tid] = iv - v;
    }
    __syncthreads();
    int eb = wt[wave] + inc - s;
    #pragma unroll
    for (int k = 0; k < 16; ++k) {
        int c = base16 + k;
        if (c < NC3) cellstart[c] = (unsigned short)(eb + loc[k]);
    }
    if (tid == 511) cellstart[NC3] = (unsigned short)(wt[7] + inc);
    __syncthreads();

    // pass 2: scatter (slot = cellstart + saved rank)
    #pragma unroll
    for (int k = 0; k < 16; ++k) {
        if (cell[k] >= 0) {
            int slot = (int)cellstart[cell[k]] + rk[k];
            if (slot < SCAP) {
                int i = k * 512 + tid;
                float4 v = pred[i];
                v.w = __int_as_float(i);         // pack original index
                spredL[slot] = v;
            }
        }
    }
    int l = tid & 3, g = tid >> 2;               // 4 lanes per row
    int row = blockIdx.x * ROWS_PB + g;
    if (l == 0) scnt[g] = 0;
    __syncthreads();

    // search: 27-cell neighborhood at LDS latency
    float4 t = truec[row];
    if (t.w >= 0.5f) {
        int cx = min((int)t.x, NCG - 1);
        int cy = min((int)t.y, NCG - 1);
        int cz = min((int)t.z, NCG - 1);
        int x0 = max(cx - 1, 0), x1 = min(cx + 1, NCG - 1);
        for (int sp = l; sp < 9; sp += 4) {
            int zz = cz - 1 + sp / 3;
            int yy = cy - 1 + sp % 3;
            if (zz < 0 || zz >= NCG || yy < 0 || yy >= NCG) continue;
            int cb = (zz * NCG + yy) * NCG;
            int s0 = cellstart[cb + x0];
            int s1 = cellstart[cb + x1 + 1];     // x-contiguous span
            for (int si = s0; si < s1; ++si) {
                float4 p = spredL[si];
                float dx = t.x - p.x, dy = t.y - p.y, dz = t.z - p.z;
                float d = sqrtf(dx * dx + dy * dy + dz * dz);
                if (d <= 1.0f) {
                    int a = atomicAdd(&scnt[g], 1);
                    if (a < CAP)
                        skey[g * CAP + a] =
                            ((unsigned long long)__float_as_uint(d) << 32)
                            | (unsigned int)__float_as_int(p.w);
                }
            }
        }
    }
    __syncthreads();
    if (l == 0) {
        int n = min(scnt[g], CAP);
        for (int a = 1; a < n; ++a) {            // (d asc, j asc) = argmin tie-break
            unsigned long long kv = skey[g * CAP + a];
            int b = a - 1;
            while (b >= 0 && skey[g * CAP + b] > kv) {
                skey[g * CAP + b + 1] = skey[g * CAP + b]; --b;
            }
            skey[g * CAP + b + 1] = kv;
        }
        scnt[g] = n;
    }
    __syncthreads();
    // allocate within the block's FIXED segment (2-wave scan of 128 counts)
    if (tid < ROWS_PB) {
        int n = scnt[tid];
        int inc2 = n;
        #pragma unroll
        for (int o = 1; o < 64; o <<= 1) {
            int u = __shfl_up(inc2, o);
            if (lane >= o) inc2 += u;
        }
        if (lane == 63) wtot[wave] = inc2;
        sst[tid] = inc2 - n;
    }
    __syncthreads();
    if (tid < ROWS_PB) {
        int st = sst[tid] + ((tid >= 64) ? wtot[0] : 0);
        int n = scnt[tid];
        int nn = n;
        if (st >= SEG_PB) nn = 0;
        else if (st + nn > SEG_PB) nn = SEG_PB - st;
        sst[tid] = st;
        scnt[tid] = nn;
        int r = blockIdx.x * ROWS_PB + tid;
        bool occ2 = (truec[r].w >= 0.5f);
        unsigned short o0v;
        if (nn > 0) o0v = (unsigned short)(blockIdx.x * SEG_PB + st);
        else o0v = occ2 ? (unsigned short)0xFFFE : (unsigned short)0xFFFF;
        o0g[r] = o0v;
        cng[r] = (unsigned char)nn;
    }
    __syncthreads();
    {
        int st = blockIdx.x * SEG_PB + sst[g];
        int nn = scnt[g];
        for (int k = l; k < nn; k += 4)
            Eg[st + k] = (unsigned short)(skey[g * CAP + k] & 0x1FFFu);
    }

    // ---- last-block handoff ----
    __threadfence();                             // release this block's stores
    __syncthreads();                             // all LDS/global work of block done
    if (tid == 0) amLast = (atomicAdd(done, 1) == NBLK - 1);
    __syncthreads();
    if (!amLast) return;
    __threadfence();                             // acquire sibling blocks' stores

    // ---- matcher overlay (build LDS dead) ----
    unsigned short* E   = (unsigned short*)(smem + OFF_E);
    unsigned short* o0s = (unsigned short*)(smem + OFF_O0S);
    unsigned char* cn8  = (unsigned char*)(smem + OFF_CN8);
    unsigned int* Hs    = (unsigned int*)(smem + OFF_HS);
    float* redf         = (float*)(smem + OFF_REDF);   // [2][8]
    int* redi           = (int*)(smem + OFF_REDI);     // [2][8]

    for (int x = tid; x < ECAP / 2; x += 512)
        ((unsigned int*)E)[x] = ((const unsigned int*)Eg)[x];
    for (int x = tid; x < NP / 2; x += 512)
        ((unsigned int*)o0s)[x] = ((const unsigned int*)o0g)[x];
    for (int x = tid; x < NP / 4; x += 512)
        ((unsigned int*)cn8)[x] = ((const unsigned int*)cng)[x];
    for (int r = tid; r < NP; r += 512) Hs[r] = INF_U;
    __syncthreads();

    // chain-following matching: H[col] = (row<<4)|pos, monotone atomicMin
    int mynocc = 0;
    for (int r0 = tid; r0 < NP; r0 += 512) {
        if (o0s[r0] != 0xFFFFu) ++mynocc;        // occupied true row
        int n = cn8[r0];
        if (!n) continue;
        int r = r0, p = 0;
        int e = o0s[r0];
        while (true) {
            unsigned int col = E[e];
            unsigned int key = ((unsigned int)r << 4) | (unsigned int)p;
            if (Hs[col] < key) {                 // sound pre-check: H only decreases
                if (++p >= n) break;
                ++e; continue;
            }
            unsigned int old = atomicMin(&Hs[col], key);
            if (old > key) {
                if (old == INF_U) break;         // claimed a free col: chain ends
                r = (int)(old >> 4);             // displaced row continues
                p = (int)(old & 15u) + 1;
                n = cn8[r];
                if (p >= n) break;
                e = o0s[r] + p;
            } else {
                if (++p >= n) break;             // better row holds it (permanent)
                ++e;
            }
        }
    }
    __syncthreads();

    // matched-only reduction (fixed order -> deterministic)
    float sdist = 0.f, sprob = 0.f;
    int nm = 0;
    for (int j = tid; j < NP; j += 512) {
        unsigned int h = Hs[j];
        if (h != INF_U) {
            int r = (int)(h >> 4);
            float4 tt = truec[r];
            float4 pp = pred[j];
            float dx = tt.x - pp.x, dy = tt.y - pp.y, dz = tt.z - pp.z;
            sdist += sqrtf(dx * dx + dy * dy + dz * dz);
            float dp = tt.w - pp.w;
            sprob += dp * dp;
            ++nm;
        }
    }
    for (int o = 32; o; o >>= 1) {
        sdist += __shfl_down(sdist, o);
        sprob += __shfl_down(sprob, o);
        nm     += __shfl_down(nm, o);
        mynocc += __shfl_down(mynocc, o);
    }
    if (lane == 0) {
        redf[wave] = sdist; redf[8 + wave] = sprob;
        redi[wave] = nm;    redi[8 + wave] = mynocc;
    }
    __syncthreads();
    if (tid == 0) {
        float S = 0.f, P = 0.f; int NM = 0, NO = 0;
        for (int w = 0; w < 8; ++w) {
            S += redf[w]; P += redf[8 + w];
            NM += redi[w]; NO += redi[8 + w];
        }
        float nmf = (float)NM;
        float unm = (float)NO - nmf;
        out[0] = (S / nmf + 10.0f * unm) + (P / nmf + unm);
    }
}

extern "C" void kernel_launch(void* const* d_in, const int* in_sizes, int n_in,
                              void* d_out, int out_size, void* d_ws, size_t ws_size,
                              hipStream_t stream) {
    const float4* pred  = (const float4*)d_in[0];
    const float4* truec = (const float4*)d_in[1];
    float* out = (float*)d_out;

    int* done           = (int*)d_ws;                    // 1 int (+pad)
    unsigned short* o0g = (unsigned short*)((char*)d_ws + 16);   // NP u16
    unsigned char* cng  = (unsigned char*)(o0g + NP);    // NP u8
    unsigned short* Eg  = (unsigned short*)(cng + NP);   // ECAP u16

    hipMemsetAsync(done, 0, 4, stream);                  // ws is 0xAA-poisoned once
    spl_fused<<<NBLK, 512, 0, stream>>>(pred, truec, o0g, cng, Eg, done, out);
}

// Round 12
// 30.484 us; speedup vs baseline: 1.9735x; 1.9735x over previous
//
#include <hip/hip_runtime.h>

#define NP      8192
#define NCG     20
#define NC3     8000        // 20^3 unit cells over [0,20)^3
#define SCAP    4608        // compact occupied-pred capacity (~4096 expected)
#define NBLK    64          // build blocks
#define ROWS_PB 128         // rows per build block
#define SEG_PB  256         // fixed entry segment per block (deterministic)
#define ECAP    (NBLK*SEG_PB)   // 16384
#define CAP     16          // per-row candidate cap (pos fits 4 bits)
#define INF_U   0xFFFFFFFFu

// ---------- K1: self-binning candidate build (64 blocks x 1024 threads) ----------
// Each block builds its own LDS bin structure (pred held in registers between
// passes), then searches the 27-cell neighborhoods of its 128 true rows at LDS
// latency. Entries land in a FIXED per-block segment -> no global counters.
__global__ __launch_bounds__(1024)
void build_cands(const float4* __restrict__ pred,
                 const float4* __restrict__ truec,
                 unsigned short* __restrict__ o0g,   // row -> entry start | 0xFFFE occ-none | 0xFFFF unocc
                 unsigned char* __restrict__ cng,    // row -> candidate count
                 unsigned short* __restrict__ Eg) {  // ECAP entry cols (sorted per row)
    __shared__ float4 spredL[SCAP];                  // 73.7KB compact occupied pred (idx in .w)
    __shared__ int cc[NC3];                          // 32KB  cell counters
    __shared__ unsigned short cellstart[NC3 + 1];    // 16KB
    __shared__ unsigned long long skey[ROWS_PB][CAP];// 16KB  per-row (d,j) keys
    __shared__ int scnt[ROWS_PB];
    __shared__ int sst[ROWS_PB];
    __shared__ int wt[16];
    __shared__ int wtot[2];
    int tid = threadIdx.x;
    int lane = tid & 63, wave = tid >> 6;

    for (int c = tid; c < NC3; c += 1024) cc[c] = 0;
    __syncthreads();

    // pass 1: count occupied pred per cell; keep pred values in registers
    float4 p[8]; int cell[8], rk[8];
    #pragma unroll
    for (int k = 0; k < 8; ++k) {
        int i = k * 1024 + tid;
        p[k] = pred[i];
        if (p[k].w >= 0.5f) {
            int cx = min((int)p[k].x, NCG - 1);
            int cy = min((int)p[k].y, NCG - 1);
            int cz = min((int)p[k].z, NCG - 1);
            cell[k] = (cz * NCG + cy) * NCG + cx;
            rk[k] = atomicAdd(&cc[cell[k]], 1);
        } else cell[k] = -1;
    }
    __syncthreads();

    // exclusive scan of 8000 cell counts (serial-8 + wave shfl + 16-wave combine)
    int base8 = tid * 8;
    int loc[8]; int s = 0;
    #pragma unroll
    for (int k = 0; k < 8; ++k) {
        int c = base8 + k;
        int v = (c < NC3) ? cc[c] : 0;
        loc[k] = s; s += v;
    }
    int inc = s;
    #pragma unroll
    for (int o = 1; o < 64; o <<= 1) {
        int t = __shfl_up(inc, o);
        if (lane >= o) inc += t;
    }
    if (lane == 63) wt[wave] = inc;
    __syncthreads();
    if (tid < 16) {
        int v = wt[tid]; int iv = v;
        #pragma unroll
        for (int o = 1; o < 16; o <<= 1) {
            int t = __shfl_up(iv, o);
            if (tid >= o) iv += t;
        }
        wt[tid] = iv - v;
    }
    __syncthreads();
    int eb = wt[wave] + inc - s;
    #pragma unroll
    for (int k = 0; k < 8; ++k) {
        int c = base8 + k;
        if (c < NC3) cellstart[c] = (unsigned short)(eb + loc[k]);
    }
    if (tid == 1023) cellstart[NC3] = (unsigned short)(wt[15] + inc);
    __syncthreads();

    // pass 2: scatter from registers (slot = cellstart + saved rank)
    #pragma unroll
    for (int k = 0; k < 8; ++k) {
        if (cell[k] >= 0) {
            int slot = (int)cellstart[cell[k]] + rk[k];
            if (slot < SCAP) {
                float4 v = p[k];
                v.w = __int_as_float(k * 1024 + tid);   // pack original index
                spredL[slot] = v;
            }
        }
    }
    int l = tid & 7, g = tid >> 3;               // 8 lanes per row, 128 rows
    int row = blockIdx.x * ROWS_PB + g;
    if (l == 0) scnt[g] = 0;
    __syncthreads();

    // search: 27-cell neighborhood at LDS latency
    float4 t = truec[row];
    if (t.w >= 0.5f) {
        int cx = min((int)t.x, NCG - 1);
        int cy = min((int)t.y, NCG - 1);
        int cz = min((int)t.z, NCG - 1);
        int x0 = max(cx - 1, 0), x1 = min(cx + 1, NCG - 1);
        for (int sp = l; sp < 9; sp += 8) {
            int zz = cz - 1 + sp / 3;
            int yy = cy - 1 + sp % 3;
            if (zz < 0 || zz >= NCG || yy < 0 || yy >= NCG) continue;
            int cb = (zz * NCG + yy) * NCG;
            int s0 = cellstart[cb + x0];
            int s1 = cellstart[cb + x1 + 1];     // x-contiguous span
            for (int si = s0; si < s1; ++si) {
                float4 pp = spredL[si];
                float dx = t.x - pp.x, dy = t.y - pp.y, dz = t.z - pp.z;
                float d = sqrtf(dx * dx + dy * dy + dz * dz);
                if (d <= 1.0f) {
                    int a = atomicAdd(&scnt[g], 1);
                    if (a < CAP)
                        skey[g][a] = ((unsigned long long)__float_as_uint(d) << 32)
                                     | (unsigned int)__float_as_int(pp.w);
                }
            }
        }
    }
    __syncthreads();
    if (l == 0) {
        int n = min(scnt[g], CAP);
        for (int a = 1; a < n; ++a) {            // (d asc, j asc) = argmin tie-break
            unsigned long long kv = skey[g][a];
            int b = a - 1;
            while (b >= 0 && skey[g][b] > kv) { skey[g][b + 1] = skey[g][b]; --b; }
            skey[g][b + 1] = kv;
        }
        scnt[g] = n;
    }
    __syncthreads();
    // allocate within the block's FIXED segment (2-wave scan of 128 counts)
    if (tid < ROWS_PB) {
        int n = scnt[tid];
        int inc2 = n;
        #pragma unroll
        for (int o = 1; o < 64; o <<= 1) {
            int u = __shfl_up(inc2, o);
            if (lane >= o) inc2 += u;
        }
        if (lane == 63) wtot[wave] = inc2;
        sst[tid] = inc2 - n;
    }
    __syncthreads();
    if (tid < ROWS_PB) {
        int st = sst[tid] + ((tid >= 64) ? wtot[0] : 0);
        int n = scnt[tid];
        int nn = n;
        if (st >= SEG_PB) nn = 0;                // P ~ 1e-10 guard
        else if (st + nn > SEG_PB) nn = SEG_PB - st;
        sst[tid] = st;
        scnt[tid] = nn;
        int r = blockIdx.x * ROWS_PB + tid;
        bool occ2 = (truec[r].w >= 0.5f);
        unsigned short o0v;
        if (nn > 0) o0v = (unsigned short)(blockIdx.x * SEG_PB + st);
        else o0v = occ2 ? (unsigned short)0xFFFE : (unsigned short)0xFFFF;
        o0g[r] = o0v;
        cng[r] = (unsigned char)nn;
    }
    __syncthreads();
    {
        int st = blockIdx.x * SEG_PB + sst[g];
        int nn = scnt[g];
        for (int k = l; k < nn; k += 8)
            Eg[st + k] = (unsigned short)(skey[g][k] & 0x1FFFu);
    }
}

// ---------- K2: LDS chain-following Gale-Shapley + matched-only reduction ----------
// H[col] = (row<<4)|pos under LDS atomicMin (monotone-decreasing). Fixed point
// == the reference's serial greedy scan (validated absmax=0.0, rounds 1-11).
__global__ __launch_bounds__(1024)
void match_reduce(const float4* __restrict__ pred,
                  const float4* __restrict__ truec,
                  const unsigned short* __restrict__ o0g,
                  const unsigned char* __restrict__ cng,
                  const unsigned short* __restrict__ Eg,
                  float* __restrict__ out) {
    __shared__ unsigned short E[ECAP];    // 32KB
    __shared__ unsigned short o0s[NP];    // 16KB
    __shared__ unsigned char cn8[NP];     // 8KB
    __shared__ unsigned int Hs[NP];       // 32KB
    __shared__ float redf[2][16];
    __shared__ int redi[2][16];
    int tid = threadIdx.x;
    #pragma unroll
    for (int x = tid; x < ECAP / 8; x += 1024)
        ((uint4*)E)[x] = ((const uint4*)Eg)[x];
    if (tid < NP / 8)
        ((uint4*)o0s)[tid] = ((const uint4*)o0g)[tid];
    if (tid < NP / 16)
        ((uint4*)cn8)[tid] = ((const uint4*)cng)[tid];
    #pragma unroll
    for (int x = tid; x < NP / 4; x += 1024)
        ((uint4*)Hs)[x] = make_uint4(INF_U, INF_U, INF_U, INF_U);
    __syncthreads();

    int mynocc = 0;
    for (int r0 = tid; r0 < NP; r0 += 1024) {
        if (o0s[r0] != 0xFFFFu) ++mynocc;        // occupied true row
        int n = cn8[r0];
        if (!n) continue;
        int r = r0, p = 0;
        int e = o0s[r0];
        while (true) {
            unsigned int col = E[e];
            unsigned int key = ((unsigned int)r << 4) | (unsigned int)p;
            if (Hs[col] < key) {                 // sound pre-check: H only decreases
                if (++p >= n) break;
                ++e; continue;
            }
            unsigned int old = atomicMin(&Hs[col], key);
            if (old > key) {
                if (old == INF_U) break;         // claimed a free col: chain ends
                r = (int)(old >> 4);             // displaced row continues
                p = (int)(old & 15u) + 1;
                n = cn8[r];
                if (p >= n) break;
                e = o0s[r] + p;
            } else {
                if (++p >= n) break;             // better row holds it (permanent)
                ++e;
            }
        }
    }
    __syncthreads();

    // matched-only reduction (fixed order -> deterministic)
    float sdist = 0.f, sprob = 0.f;
    int nm = 0;
    for (int j = tid; j < NP; j += 1024) {
        unsigned int h = Hs[j];
        if (h != INF_U) {
            int r = (int)(h >> 4);
            float4 tt = truec[r];
            float4 pp = pred[j];
            float dx = tt.x - pp.x, dy = tt.y - pp.y, dz = tt.z - pp.z;
            sdist += sqrtf(dx * dx + dy * dy + dz * dz);
            float dp = tt.w - pp.w;
            sprob += dp * dp;
            ++nm;
        }
    }
    for (int o = 32; o; o >>= 1) {
        sdist += __shfl_down(sdist, o);
        sprob += __shfl_down(sprob, o);
        nm     += __shfl_down(nm, o);
        mynocc += __shfl_down(mynocc, o);
    }
    int wave = tid >> 6, lane = tid & 63;
    if (lane == 0) {
        redf[0][wave] = sdist; redf[1][wave] = sprob;
        redi[0][wave] = nm;    redi[1][wave] = mynocc;
    }
    __syncthreads();
    if (tid == 0) {
        float S = 0.f, P = 0.f; int NM = 0, NO = 0;
        for (int w = 0; w < 16; ++w) {
            S += redf[0][w]; P += redf[1][w];
            NM += redi[0][w]; NO += redi[1][w];
        }
        float nmf = (float)NM;
        float unm = (float)NO - nmf;
        out[0] = (S / nmf + 10.0f * unm) + (P / nmf + unm);
    }
}

extern "C" void kernel_launch(void* const* d_in, const int* in_sizes, int n_in,
                              void* d_out, int out_size, void* d_ws, size_t ws_size,
                              hipStream_t stream) {
    const float4* pred  = (const float4*)d_in[0];
    const float4* truec = (const float4*)d_in[1];
    float* out = (float*)d_out;

    unsigned short* o0g = (unsigned short*)d_ws;        // NP u16
    unsigned char* cng  = (unsigned char*)(o0g + NP);   // NP u8 (pad to 16B below)
    unsigned short* Eg  = (unsigned short*)((char*)d_ws + NP * 2 + NP + 16 - ((NP * 2 + NP) % 16)); // ECAP u16, 16B aligned

    build_cands <<<NBLK, 1024, 0, stream>>>(pred, truec, o0g, cng, Eg);
    match_reduce<<<1,    1024, 0, stream>>>(pred, truec, o0g, cng, Eg, out);
}

// Round 13
// 29.541 us; speedup vs baseline: 2.0365x; 1.0319x over previous
//
#include <hip/hip_runtime.h>

#define NP      8192
#define NCG     20
#define NC3     8000        // 20^3 unit cells over [0,20)^3
#define CELLCAP 8           // fixed u16 slots per cell (validated R5/R8)
#define NBLK    128         // build blocks
#define ROWS_PB 64          // rows per build block (1024 threads, 16 lanes/row)
#define SEG_PB  160         // fixed entry segment per block (7.7 sigma headroom)
#define ECAP    (NBLK*SEG_PB)   // 20480
#define CAP     16          // per-row candidate cap (pos fits 4 bits)
#define INF_U   0xFFFFFFFFu

// ---------- K1: one-pass-binning candidate build (128 blocks x 1024 threads) ----------
// Bin: slot[cell*8+rank] = pred index, rank via packed-u16-pair LDS atomicAdd.
// No scan, no scatter pass, no staging copy. Search reads pred[j] from L2
// (scattered but ~2 loads/thread at 16 waves -> latency-hidden).
__global__ __launch_bounds__(1024)
void build_cands(const float4* __restrict__ pred,
                 const float4* __restrict__ truec,
                 unsigned short* __restrict__ o0g,   // row -> entry start | 0xFFFE occ-none | 0xFFFF unocc
                 unsigned char* __restrict__ cng,    // row -> candidate count
                 unsigned short* __restrict__ Eg) {  // ECAP entry cols (sorted per row)
    __shared__ unsigned short slot[NC3 * CELLCAP];     // 128000 B
    __shared__ unsigned int cc[NC3 / 2];               // 16000 B (u16 counts, 2/u32)
    __shared__ unsigned long long skey[ROWS_PB][CAP];  // 8192 B
    __shared__ int scnt[ROWS_PB];
    __shared__ int sst[ROWS_PB];
    int tid = threadIdx.x;
    int g = tid >> 4, l = tid & 15;                    // 16 lanes per row

    for (int c = tid; c < NC3 / 2; c += 1024) cc[c] = 0;
    if (l == 0) scnt[g] = 0;
    __syncthreads();

    // one-pass bin: count + slot write together
    #pragma unroll
    for (int k = 0; k < 8; ++k) {
        int i = k * 1024 + tid;
        float4 p = pred[i];
        if (p.w >= 0.5f) {
            int cx = min((int)p.x, NCG - 1);
            int cy = min((int)p.y, NCG - 1);
            int cz = min((int)p.z, NCG - 1);
            int cell = (cz * NCG + cy) * NCG + cx;
            int sh = (cell & 1) * 16;
            unsigned int old = atomicAdd(&cc[cell >> 1], 1u << sh);
            int rk = (int)((old >> sh) & 0xFFFFu);
            if (rk < CELLCAP) slot[cell * CELLCAP + rk] = (unsigned short)i;
        }
    }
    __syncthreads();

    // search: 27-cell neighborhood; slots in LDS, pred[j] from L2
    int row = blockIdx.x * ROWS_PB + g;
    float4 t = truec[row];
    if (t.w >= 0.5f) {
        int cx = min((int)t.x, NCG - 1);
        int cy = min((int)t.y, NCG - 1);
        int cz = min((int)t.z, NCG - 1);
        for (int ci = l; ci < 27; ci += 16) {
            int zz = cz + ci / 9 - 1;
            int yy = cy + (ci / 3) % 3 - 1;
            int xx = cx + ci % 3 - 1;
            if (zz < 0 || zz >= NCG || yy < 0 || yy >= NCG || xx < 0 || xx >= NCG)
                continue;
            int cell = (zz * NCG + yy) * NCG + xx;
            int cnt = (int)((cc[cell >> 1] >> ((cell & 1) * 16)) & 0xFFFFu);
            if (cnt > CELLCAP) cnt = CELLCAP;
            int sbase = cell * CELLCAP;
            for (int k = 0; k < cnt; ++k) {
                int j = slot[sbase + k];
                float4 pp = pred[j];
                float dx = t.x - pp.x, dy = t.y - pp.y, dz = t.z - pp.z;
                float d = sqrtf(dx * dx + dy * dy + dz * dz);
                if (d <= 1.0f) {
                    int a = atomicAdd(&scnt[g], 1);
                    if (a < CAP)
                        skey[g][a] = ((unsigned long long)__float_as_uint(d) << 32)
                                     | (unsigned int)j;
                }
            }
        }
    }
    __syncthreads();
    if (l == 0) {
        int n = min(scnt[g], CAP);
        for (int a = 1; a < n; ++a) {            // (d asc, j asc) = argmin tie-break
            unsigned long long kv = skey[g][a];
            int b = a - 1;
            while (b >= 0 && skey[g][b] > kv) { skey[g][b + 1] = skey[g][b]; --b; }
            skey[g][b + 1] = kv;
        }
        scnt[g] = n;
    }
    __syncthreads();
    // allocate within the block's FIXED segment (single-wave scan of 64 counts)
    if (tid < ROWS_PB) {
        int n = scnt[tid];
        int inc = n;
        #pragma unroll
        for (int o = 1; o < 64; o <<= 1) {
            int u = __shfl_up(inc, o);
            if (tid >= o) inc += u;
        }
        int st = inc - n;
        int nn = n;
        if (st >= SEG_PB) nn = 0;                // ~7.7 sigma guard
        else if (st + nn > SEG_PB) nn = SEG_PB - st;
        sst[tid] = st;
        scnt[tid] = nn;
        int r = blockIdx.x * ROWS_PB + tid;
        bool occ2 = (truec[r].w >= 0.5f);
        unsigned short o0v;
        if (nn > 0) o0v = (unsigned short)(blockIdx.x * SEG_PB + st);
        else o0v = occ2 ? (unsigned short)0xFFFE : (unsigned short)0xFFFF;
        o0g[r] = o0v;
        cng[r] = (unsigned char)nn;
    }
    __syncthreads();
    {
        int st = blockIdx.x * SEG_PB + sst[g];
        int nn = scnt[g];
        for (int k = l; k < nn; k += 16)
            Eg[st + k] = (unsigned short)(skey[g][k] & 0x1FFFu);
    }
}

// ---------- K2: LDS chain-following Gale-Shapley + matched-only reduction ----------
// H[col] = (row<<4)|pos under LDS atomicMin (monotone-decreasing). Fixed point
// == the reference's serial greedy scan (validated absmax=0.0, rounds 1-12).
__global__ __launch_bounds__(1024)
void match_reduce(const float4* __restrict__ pred,
                  const float4* __restrict__ truec,
                  const unsigned short* __restrict__ o0g,
                  const unsigned char* __restrict__ cng,
                  const unsigned short* __restrict__ Eg,
                  float* __restrict__ out) {
    __shared__ unsigned short E[ECAP];    // 40KB
    __shared__ unsigned short o0s[NP];    // 16KB
    __shared__ unsigned char cn8[NP];     // 8KB
    __shared__ unsigned int Hs[NP];       // 32KB
    __shared__ float redf[2][16];
    __shared__ int redi[2][16];
    int tid = threadIdx.x;
    #pragma unroll
    for (int x = tid; x < ECAP / 8; x += 1024)
        ((uint4*)E)[x] = ((const uint4*)Eg)[x];
    if (tid < NP / 8)
        ((uint4*)o0s)[tid] = ((const uint4*)o0g)[tid];
    if (tid < NP / 16)
        ((uint4*)cn8)[tid] = ((const uint4*)cng)[tid];
    #pragma unroll
    for (int x = tid; x < NP / 4; x += 1024)
        ((uint4*)Hs)[x] = make_uint4(INF_U, INF_U, INF_U, INF_U);
    __syncthreads();

    int mynocc = 0;
    for (int r0 = tid; r0 < NP; r0 += 1024) {
        if (o0s[r0] != 0xFFFFu) ++mynocc;        // occupied true row
        int n = cn8[r0];
        if (!n) continue;
        int r = r0, p = 0;
        int e = o0s[r0];
        while (true) {
            unsigned int col = E[e];
            unsigned int key = ((unsigned int)r << 4) | (unsigned int)p;
            if (Hs[col] < key) {                 // sound pre-check: H only decreases
                if (++p >= n) break;
                ++e; continue;
            }
            unsigned int old = atomicMin(&Hs[col], key);
            if (old > key) {
                if (old == INF_U) break;         // claimed a free col: chain ends
                r = (int)(old >> 4);             // displaced row continues
                p = (int)(old & 15u) + 1;
                n = cn8[r];
                if (p >= n) break;
                e = o0s[r] + p;
            } else {
                if (++p >= n) break;             // better row holds it (permanent)
                ++e;
            }
        }
    }
    __syncthreads();

    // matched-only reduction (fixed order -> deterministic)
    float sdist = 0.f, sprob = 0.f;
    int nm = 0;
    for (int j = tid; j < NP; j += 1024) {
        unsigned int h = Hs[j];
        if (h != INF_U) {
            int r = (int)(h >> 4);
            float4 tt = truec[r];
            float4 pp = pred[j];
            float dx = tt.x - pp.x, dy = tt.y - pp.y, dz = tt.z - pp.z;
            sdist += sqrtf(dx * dx + dy * dy + dz * dz);
            float dp = tt.w - pp.w;
            sprob += dp * dp;
            ++nm;
        }
    }
    for (int o = 32; o; o >>= 1) {
        sdist += __shfl_down(sdist, o);
        sprob += __shfl_down(sprob, o);
        nm     += __shfl_down(nm, o);
        mynocc += __shfl_down(mynocc, o);
    }
    int wave = tid >> 6, lane = tid & 63;
    if (lane == 0) {
        redf[0][wave] = sdist; redf[1][wave] = sprob;
        redi[0][wave] = nm;    redi[1][wave] = mynocc;
    }
    __syncthreads();
    if (tid == 0) {
        float S = 0.f, P = 0.f; int NM = 0, NO = 0;
        for (int w = 0; w < 16; ++w) {
            S += redf[0][w]; P += redf[1][w];
            NM += redi[0][w]; NO += redi[1][w];
        }
        float nmf = (float)NM;
        float unm = (float)NO - nmf;
        out[0] = (S / nmf + 10.0f * unm) + (P / nmf + unm);
    }
}

extern "C" void kernel_launch(void* const* d_in, const int* in_sizes, int n_in,
                              void* d_out, int out_size, void* d_ws, size_t ws_size,
                              hipStream_t stream) {
    const float4* pred  = (const float4*)d_in[0];
    const float4* truec = (const float4*)d_in[1];
    float* out = (float*)d_out;

    unsigned short* o0g = (unsigned short*)d_ws;               // NP u16 (16KB)
    unsigned char* cng  = (unsigned char*)(o0g + NP);          // NP u8  (8KB)
    unsigned short* Eg  = (unsigned short*)((char*)d_ws + 24576); // ECAP u16, 16B aligned

    build_cands <<<NBLK, 1024, 0, stream>>>(pred, truec, o0g, cng, Eg);
    match_reduce<<<1,    1024, 0, stream>>>(pred, truec, o0g, cng, Eg, out);
}

// Round 14
// 28.837 us; speedup vs baseline: 2.0862x; 1.0244x over previous
//
#include <hip/hip_runtime.h>

#define NP      8192
#define NCG     20
#define NC3     8000        // 20^3 unit cells over [0,20)^3
#define CELLCAP 8           // fixed u16 slots per cell (validated R5/R8/R12/R13)
#define NBLK    128         // build blocks
#define ROWS_PB 64          // rows per build block (1024 threads, 16 lanes/row)
#define SEG_PB  160         // fixed entry segment per block (7.7 sigma headroom)
#define ECAP    (NBLK*SEG_PB)   // 20480
#define CAP     16          // per-row candidate cap (pos fits 4 bits)
#define INF_U   0xFFFFFFFFu

// ---------- K1: one-pass-binning candidate build (128 blocks x 1024 threads) ----------
// Identical to R13 except the per-row descriptor is packed into one u32:
// oc[r] = (occupied<<31) | (entry_start<<8) | count.
__global__ __launch_bounds__(1024)
void build_cands(const float4* __restrict__ pred,
                 const float4* __restrict__ truec,
                 unsigned int* __restrict__ ocg,     // row -> packed descriptor
                 unsigned short* __restrict__ Eg) {  // ECAP entry cols (sorted per row)
    __shared__ unsigned short slot[NC3 * CELLCAP];     // 128000 B
    __shared__ unsigned int cc[NC3 / 2];               // 16000 B (u16 counts, 2/u32)
    __shared__ unsigned long long skey[ROWS_PB][CAP];  // 8192 B
    __shared__ int scnt[ROWS_PB];
    __shared__ int sst[ROWS_PB];
    int tid = threadIdx.x;
    int g = tid >> 4, l = tid & 15;                    // 16 lanes per row

    for (int c = tid; c < NC3 / 2; c += 1024) cc[c] = 0;
    if (l == 0) scnt[g] = 0;
    __syncthreads();

    // one-pass bin: count + slot write together
    #pragma unroll
    for (int k = 0; k < 8; ++k) {
        int i = k * 1024 + tid;
        float4 p = pred[i];
        if (p.w >= 0.5f) {
            int cx = min((int)p.x, NCG - 1);
            int cy = min((int)p.y, NCG - 1);
            int cz = min((int)p.z, NCG - 1);
            int cell = (cz * NCG + cy) * NCG + cx;
            int sh = (cell & 1) * 16;
            unsigned int old = atomicAdd(&cc[cell >> 1], 1u << sh);
            int rk = (int)((old >> sh) & 0xFFFFu);
            if (rk < CELLCAP) slot[cell * CELLCAP + rk] = (unsigned short)i;
        }
    }
    __syncthreads();

    // search: 27-cell neighborhood; slots in LDS, pred[j] from L2
    int row = blockIdx.x * ROWS_PB + g;
    float4 t = truec[row];
    if (t.w >= 0.5f) {
        int cx = min((int)t.x, NCG - 1);
        int cy = min((int)t.y, NCG - 1);
        int cz = min((int)t.z, NCG - 1);
        for (int ci = l; ci < 27; ci += 16) {
            int zz = cz + ci / 9 - 1;
            int yy = cy + (ci / 3) % 3 - 1;
            int xx = cx + ci % 3 - 1;
            if (zz < 0 || zz >= NCG || yy < 0 || yy >= NCG || xx < 0 || xx >= NCG)
                continue;
            int cell = (zz * NCG + yy) * NCG + xx;
            int cnt = (int)((cc[cell >> 1] >> ((cell & 1) * 16)) & 0xFFFFu);
            if (cnt > CELLCAP) cnt = CELLCAP;
            int sbase = cell * CELLCAP;
            for (int k = 0; k < cnt; ++k) {
                int j = slot[sbase + k];
                float4 pp = pred[j];
                float dx = t.x - pp.x, dy = t.y - pp.y, dz = t.z - pp.z;
                float d = sqrtf(dx * dx + dy * dy + dz * dz);
                if (d <= 1.0f) {
                    int a = atomicAdd(&scnt[g], 1);
                    if (a < CAP)
                        skey[g][a] = ((unsigned long long)__float_as_uint(d) << 32)
                                     | (unsigned int)j;
                }
            }
        }
    }
    __syncthreads();
    if (l == 0) {
        int n = min(scnt[g], CAP);
        for (int a = 1; a < n; ++a) {            // (d asc, j asc) = argmin tie-break
            unsigned long long kv = skey[g][a];
            int b = a - 1;
            while (b >= 0 && skey[g][b] > kv) { skey[g][b + 1] = skey[g][b]; --b; }
            skey[g][b + 1] = kv;
        }
        scnt[g] = n;
    }
    __syncthreads();
    // allocate within the block's FIXED segment (single-wave scan of 64 counts)
    if (tid < ROWS_PB) {
        int n = scnt[tid];
        int inc = n;
        #pragma unroll
        for (int o = 1; o < 64; o <<= 1) {
            int u = __shfl_up(inc, o);
            if (tid >= o) inc += u;
        }
        int st = inc - n;
        int nn = n;
        if (st >= SEG_PB) nn = 0;                // ~7.7 sigma guard
        else if (st + nn > SEG_PB) nn = SEG_PB - st;
        sst[tid] = st;
        scnt[tid] = nn;
        int r = blockIdx.x * ROWS_PB + tid;
        unsigned int occ2 = (truec[r].w >= 0.5f) ? 1u : 0u;
        unsigned int start = (nn > 0) ? (unsigned int)(blockIdx.x * SEG_PB + st) : 0u;
        ocg[r] = (occ2 << 31) | (start << 8) | (unsigned int)nn;
    }
    __syncthreads();
    {
        int st = blockIdx.x * SEG_PB + sst[g];
        int nn = scnt[g];
        for (int k = l; k < nn; k += 16)
            Eg[st + k] = (unsigned short)(skey[g][k] & 0x1FFFu);
    }
}

// ---------- K2: LDS chain-following Gale-Shapley, 2 interleaved chains/thread ----------
// H[col] = (row<<4)|pos under LDS atomicMin (monotone-decreasing). Direct
// atomicMin (no pre-check): old > key => won, else advance. Fixed point ==
// the reference's serial greedy scan (validated absmax=0.0, rounds 1-13).
__global__ __launch_bounds__(1024)
void match_reduce(const float4* __restrict__ pred,
                  const float4* __restrict__ truec,
                  const unsigned int* __restrict__ ocg,
                  const unsigned short* __restrict__ Eg,
                  float* __restrict__ out) {
    __shared__ unsigned short E[ECAP];    // 40KB
    __shared__ unsigned int ocs[NP];      // 32KB packed row descriptors
    __shared__ unsigned int Hs[NP];       // 32KB
    __shared__ float redf[2][16];
    __shared__ int redi[2][16];
    int tid = threadIdx.x;
    #pragma unroll
    for (int x = tid; x < ECAP / 8; x += 1024)
        ((uint4*)E)[x] = ((const uint4*)Eg)[x];
    #pragma unroll
    for (int x = tid; x < NP / 4; x += 1024)
        ((uint4*)ocs)[x] = ((const uint4*)ocg)[x];
    #pragma unroll
    for (int x = tid; x < NP / 4; x += 1024)
        ((uint4*)Hs)[x] = make_uint4(INF_U, INF_U, INF_U, INF_U);
    __syncthreads();

    int mynocc = 0;
    #pragma unroll
    for (int base = 0; base < NP; base += 2048) {
        int rA = base + tid, rB = base + 1024 + tid;
        unsigned int ocA = ocs[rA], ocB = ocs[rB];
        mynocc += (int)(ocA >> 31) + (int)(ocB >> 31);
        int nA = (int)(ocA & 0xFFu), nB = (int)(ocB & 0xFFu);
        int rAc = rA, rBc = rB;
        int pA = 0, pB = 0;
        int eA = (int)((ocA >> 8) & 0x7FFFFFu);
        int eB = (int)((ocB >> 8) & 0x7FFFFFu);
        bool aA = (nA > 0), aB = (nB > 0);
        while (aA || aB) {
            unsigned int colA = 0, colB = 0;
            if (aA) colA = E[eA];
            if (aB) colB = E[eB];
            unsigned int keyA = ((unsigned int)rAc << 4) | (unsigned int)pA;
            unsigned int keyB = ((unsigned int)rBc << 4) | (unsigned int)pB;
            unsigned int oldA = 0, oldB = 0;
            if (aA) oldA = atomicMin(&Hs[colA], keyA);
            if (aB) oldB = atomicMin(&Hs[colB], keyB);
            if (aA) {
                if (oldA > keyA) {
                    if (oldA == INF_U) aA = false;   // claimed free col
                    else {                           // displaced old holder: continue it
                        rAc = (int)(oldA >> 4);
                        pA = (int)(oldA & 15u) + 1;
                        unsigned int oc = ocs[rAc];
                        nA = (int)(oc & 0xFFu);
                        if (pA >= nA) aA = false;
                        else eA = (int)((oc >> 8) & 0x7FFFFFu) + pA;
                    }
                } else {                             // better row holds it: advance
                    if (++pA >= nA) aA = false;
                    else ++eA;
                }
            }
            if (aB) {
                if (oldB > keyB) {
                    if (oldB == INF_U) aB = false;
                    else {
                        rBc = (int)(oldB >> 4);
                        pB = (int)(oldB & 15u) + 1;
                        unsigned int oc = ocs[rBc];
                        nB = (int)(oc & 0xFFu);
                        if (pB >= nB) aB = false;
                        else eB = (int)((oc >> 8) & 0x7FFFFFu) + pB;
                    }
                } else {
                    if (++pB >= nB) aB = false;
                    else ++eB;
                }
            }
        }
    }
    __syncthreads();

    // matched-only reduction (fixed order -> deterministic)
    float sdist = 0.f, sprob = 0.f;
    int nm = 0;
    for (int j = tid; j < NP; j += 1024) {
        unsigned int h = Hs[j];
        if (h != INF_U) {
            int r = (int)(h >> 4);
            float4 tt = truec[r];
            float4 pp = pred[j];
            float dx = tt.x - pp.x, dy = tt.y - pp.y, dz = tt.z - pp.z;
            sdist += sqrtf(dx * dx + dy * dy + dz * dz);
            float dp = tt.w - pp.w;
            sprob += dp * dp;
            ++nm;
        }
    }
    for (int o = 32; o; o >>= 1) {
        sdist += __shfl_down(sdist, o);
        sprob += __shfl_down(sprob, o);
        nm     += __shfl_down(nm, o);
        mynocc += __shfl_down(mynocc, o);
    }
    int wave = tid >> 6, lane = tid & 63;
    if (lane == 0) {
        redf[0][wave] = sdist; redf[1][wave] = sprob;
        redi[0][wave] = nm;    redi[1][wave] = mynocc;
    }
    __syncthreads();
    if (tid == 0) {
        float S = 0.f, P = 0.f; int NM = 0, NO = 0;
        for (int w = 0; w < 16; ++w) {
            S += redf[0][w]; P += redf[1][w];
            NM += redi[0][w]; NO += redi[1][w];
        }
        float nmf = (float)NM;
        float unm = (float)NO - nmf;
        out[0] = (S / nmf + 10.0f * unm) + (P / nmf + unm);
    }
}

extern "C" void kernel_launch(void* const* d_in, const int* in_sizes, int n_in,
                              void* d_out, int out_size, void* d_ws, size_t ws_size,
                              hipStream_t stream) {
    const float4* pred  = (const float4*)d_in[0];
    const float4* truec = (const float4*)d_in[1];
    float* out = (float*)d_out;

    unsigned int* ocg   = (unsigned int*)d_ws;          // NP u32 (32KB)
    unsigned short* Eg  = (unsigned short*)(ocg + NP);  // ECAP u16 (40KB)

    build_cands <<<NBLK, 1024, 0, stream>>>(pred, truec, ocg, Eg);
    match_reduce<<<1,    1024, 0, stream>>>(pred, truec, ocg, Eg, out);
}